// Round 4
// baseline (2995.423 us; speedup 1.0000x reference)
//
#include <hip/hip_runtime.h>
#include <hip/hip_cooperative_groups.h>

namespace cg = cooperative_groups;

typedef unsigned short u16;
typedef unsigned int   u32;
typedef __attribute__((ext_vector_type(4))) float f32x4;
typedef __attribute__((ext_vector_type(8))) u16   u16x8;
typedef __attribute__((ext_vector_type(4))) u16   u16x4;
typedef __attribute__((ext_vector_type(4))) u32   u32x4;

// ---------------- helpers ----------------
__device__ __forceinline__ u16 f2bf(float x) {
  u32 u = __builtin_bit_cast(u32, x);
  u = (u + 0x7fffu + ((u >> 16) & 1u)) >> 16;
  return (u16)u;
}
__device__ __forceinline__ float bf2f(u16 h) {
  return __builtin_bit_cast(float, (u32)h << 16);
}
__device__ __forceinline__ float fast_sig(float x) { return 1.f / (1.f + __expf(-x)); }
__device__ __forceinline__ float fast_tanh(float x) {
  float e = __expf(2.f * x);
  return 1.f - 2.f / (e + 1.f);
}

__device__ __forceinline__ f32x4 mfma_bf16(u16x8 a, u16x8 b, f32x4 c) {
  asm volatile("v_mfma_f32_16x16x32_bf16 %0, %1, %2, %0" : "+v"(c) : "v"(a), "v"(b));
  return c;
}

__device__ __forceinline__ void gload_lds16(const void* g, void* l) {
  __builtin_amdgcn_global_load_lds(
      (__attribute__((address_space(1))) u32*)g,
      (__attribute__((address_space(3))) u32*)l, 16, 0, 0);
}

// ---------------- fused prep: all conversions + packing + zeroing, one kernel ----------------
__device__ __forceinline__ void conv4(const float* __restrict__ s, u16* __restrict__ d, int i) {
  f32x4 v = *(const f32x4*)(s + i);
  u16x4 o;
  o.x = f2bf(v.x); o.y = f2bf(v.y); o.z = f2bf(v.z); o.w = f2bf(v.w);
  *(u16x4*)(d + i) = o;
}

__global__ __launch_bounds__(256) void k_prep(
    const float* __restrict__ batch_H, const float* __restrict__ W_i2h,
    const float* __restrict__ emb, const float* __restrict__ W_ih,
    const float* __restrict__ W_h2h, const float* __restrict__ W_hh,
    const float* __restrict__ W_gen, const float* __restrict__ b_ih,
    const float* __restrict__ b_hh,
    u16* __restrict__ bHb, u16* __restrict__ Wi2hb, u16* __restrict__ embb,
    u16* __restrict__ Wihb, u16* __restrict__ Whcatb, u16* __restrict__ Wgenb,
    float* __restrict__ biascat, u16* __restrict__ Acat, float* __restrict__ cst) {
  const u32 u = blockIdx.x * 256 + threadIdx.x;
  if (u < 2097152u) { conv4(batch_H, bHb, u * 4); return; }
  if (u < 2162688u) { conv4(W_i2h, Wi2hb, (u - 2097152u) * 4); return; }
  if (u < 2586624u) { conv4(emb, embb, (u - 2162688u) * 4); return; }
  if (u < 2979840u) { conv4(W_ih, Wihb, (u - 2586624u) * 4); return; }
  if (u < 3307520u) {  // Whcat = [W_h2h ; W_hh], 2560 x 512
    int i = (u - 2979840u) * 4;
    int r = i >> 9, c = i & 511;
    const float* src = (r < 512) ? (W_h2h + (size_t)r * 512 + c)
                                 : (W_hh + (size_t)(r - 512) * 512 + c);
    f32x4 v = *(const f32x4*)src;
    u16x4 o;
    o.x = f2bf(v.x); o.y = f2bf(v.y); o.z = f2bf(v.z); o.w = f2bf(v.w);
    *(u16x4*)(Whcatb + i) = o;
    return;
  }
  if (u < 4159488u) {  // Wgen padded to 6656 rows
    int i = (u - 3307520u) * 4;
    int r = i >> 9;
    if (r < 6624) conv4(W_gen, Wgenb, i);
    else *(u16x4*)(Wgenb + i) = (u16x4){0, 0, 0, 0};
    return;
  }
  if (u < 4160000u) {  // biascat
    int j = (u - 4159488u) * 4;
    f32x4 a = *(const f32x4*)(b_ih + j), b = *(const f32x4*)(b_hh + j);
    f32x4 r = {a.x + b.x, a.y + b.y, a.z + b.z, a.w + b.w};
    *(f32x4*)(biascat + j) = r;
    return;
  }
  if (u < 4200960u) {  // zero Acat (16B units)
    *(u32x4*)((char*)Acat + (size_t)(u - 4160000u) * 16) = (u32x4){0, 0, 0, 0};
    return;
  }
  if (u < 4233728u) {  // zero cst
    *(u32x4*)((char*)cst + (size_t)(u - 4200960u) * 16) = (u32x4){0, 0, 0, 0};
    return;
  }
}

// ---------------- big GEMM: C[M,N] = A[M,K] * B[N,K]^T (+bias), BK=32 ----------------
// OUT_MODE: 1 = f32 + bias, 2 = bf16 (no bias)
template <int BM, int BN, int WM, int WN, int OUT_MODE>
__global__ __launch_bounds__(256) void gemm_bt(const u16* __restrict__ A, int lda,
                                               const u16* __restrict__ B, int ldb,
                                               const float* __restrict__ bias,
                                               float* __restrict__ Cf, u16* __restrict__ Cb,
                                               int ldc, int Nreal, int K) {
  static_assert((BM / WM) * (BN / WN) == 4, "4 waves");
  constexpr int FM = WM / 16, FN = WN / 16;
  constexpr int NWC = BN / WN;
  constexpr int CHA = (BM * 4) / 256, CHB = (BN * 4) / 256;
  __shared__ __align__(16) u16 sA[BM * 32];
  __shared__ __align__(16) u16 sB[BN * 32];
  const int tid = threadIdx.x;
  const int lane = tid & 63, wave = tid >> 6;
  const int wr = wave / NWC, wc = wave % NWC;
  const int l15 = lane & 15, lhi = lane >> 4;
  const int m0 = blockIdx.y * BM, n0 = blockIdx.x * BN;

  f32x4 acc[FM][FN];
#pragma unroll
  for (int i = 0; i < FM; ++i)
#pragma unroll
    for (int j = 0; j < FN; ++j) acc[i][j] = 0.f;

  for (int k0 = 0; k0 < K; k0 += 32) {
    __syncthreads();
#pragma unroll
    for (int j = 0; j < CHA; ++j) {
      int idx = j * 256 + tid;
      int row = idx >> 2, cc = idx & 3;
      int c = cc ^ ((row >> 1) & 3);
      gload_lds16(A + (size_t)(m0 + row) * lda + (k0 + c * 8), sA + idx * 8);
    }
#pragma unroll
    for (int j = 0; j < CHB; ++j) {
      int idx = j * 256 + tid;
      int row = idx >> 2, cc = idx & 3;
      int c = cc ^ ((row >> 1) & 3);
      gload_lds16(B + (size_t)(n0 + row) * ldb + (k0 + c * 8), sB + idx * 8);
    }
    __syncthreads();

    u16x8 av[FM], bv[FN];
#pragma unroll
    for (int mi = 0; mi < FM; ++mi) {
      int row = wr * WM + mi * 16 + l15;
      int ch = row * 4 + (lhi ^ ((row >> 1) & 3));
      av[mi] = *(const u16x8*)(sA + ch * 8);
    }
#pragma unroll
    for (int ni = 0; ni < FN; ++ni) {
      int row = wc * WN + ni * 16 + l15;
      int ch = row * 4 + (lhi ^ ((row >> 1) & 3));
      bv[ni] = *(const u16x8*)(sB + ch * 8);
    }
#pragma unroll
    for (int mi = 0; mi < FM; ++mi)
#pragma unroll
      for (int ni = 0; ni < FN; ++ni) acc[mi][ni] = mfma_bf16(av[mi], bv[ni], acc[mi][ni]);
  }

  asm volatile("s_nop 7\ns_nop 7\ns_nop 7");  // MFMA->VALU hazard guard

#pragma unroll
  for (int mi = 0; mi < FM; ++mi) {
#pragma unroll
    for (int ni = 0; ni < FN; ++ni) {
      int col = n0 + wc * WN + ni * 16 + l15;
      if (col < Nreal) {
        float bvv = (OUT_MODE == 1) ? bias[col] : 0.f;
#pragma unroll
        for (int r = 0; r < 4; ++r) {
          int row = m0 + wr * WM + mi * 16 + lhi * 4 + r;
          float v = acc[mi][ni][r] + bvv;
          if (OUT_MODE == 2)
            Cb[(size_t)row * ldc + col] = f2bf(v);
          else
            Cf[(size_t)row * ldc + col] = v;
        }
      }
    }
  }
}

// ---------------- persistent cooperative recurrence kernel ----------------
// grid = 256 blocks (1/CU), 256 threads. Per step:
//   C: hp+gh GEMM  h@[W_h2h;W_hh]^T  (160 tiles, BM=32 BN=128 K=512)  -> hpbuf, ghbuf
//   A: attention per b (Hproj/batch_H LDS-resident, loaded once)      -> Acat ctx|ce
//   B: gates GEMM ([ctx|ce]@W_ih^T K=768) + gh + bias + LSTM          -> h, c, hsb
__global__ __launch_bounds__(256, 1) void coop_loop(
    const u16* __restrict__ Hproj, const u16* __restrict__ bHb,
    const u16* __restrict__ Whcatb, const u16* __restrict__ Wihb,
    const float* __restrict__ b_h2h, const float* __restrict__ wsc,
    const u16* __restrict__ embb, const int* __restrict__ text,
    u16* __restrict__ Acat, float* __restrict__ hpbuf, float* __restrict__ ghbuf,
    float* __restrict__ cst, u16* __restrict__ hsb, const float* __restrict__ biascat) {
  __shared__ __align__(16) u16 hp_lds[32768];  // Hproj[b], 64 KB, bank-swizzled
  __shared__ __align__(16) u16 bh_lds[32768];  // batch_H[b], 64 KB, linear
  __shared__ __align__(16) char gbuf[20480];   // GEMM staging (C/B) + gate exchange
  __shared__ float hpsp[528];                  // padded hp: j -> j + (j>>5)
  __shared__ float wssp[528];
  __shared__ float es[64];

  cg::grid_group grid = cg::this_grid();
  const int tid = threadIdx.x;
  const int bid = blockIdx.x;  // == batch index in phase A
  const int lane = tid & 63, wave = tid >> 6;
  const int l15 = lane & 15, lhi = lane >> 4;

  // ---- one-time init: LDS-cache Hproj[bid] (swizzled) + batch_H[bid]; w_score padded
#pragma unroll
  for (int i = 0; i < 16; ++i) {
    int q = i * 256 + tid;  // 16B chunk id, 4096 per block
    int t = q >> 6, c = (q >> 2) & 15, w = q & 3;
    int pc = (c + (c >> 2)) & 3;  // spreads 16 column-chunks over 8 bank-quads
    u16x8 hv = *(const u16x8*)(Hproj + (size_t)bid * 32768 + (size_t)q * 8);
    *(u16x8*)((char*)hp_lds + t * 1024 + c * 64 + ((w ^ pc) << 4)) = hv;
    u16x8 bv = *(const u16x8*)(bHb + (size_t)bid * 32768 + (size_t)q * 8);
    *(u16x8*)((char*)bh_lds + q * 16) = bv;
  }
  {
    int j0 = tid * 2;
    int pi = j0 + (j0 >> 5);
    wssp[pi] = wsc[j0];
    wssp[pi + 1] = wsc[j0 + 1];
  }

  for (int s = 0; s < 26; ++s) {
    // ---------- phase C: hp + gh GEMM ----------
    if (bid < 160) {
      u16* sA = (u16*)gbuf;            // 32 x 64
      u16* sB = (u16*)(gbuf + 4096);   // 128 x 64
      const int b0 = (bid / 20) * 32, n0 = (bid % 20) * 128;
      const int wr = wave >> 1, wc = wave & 1;  // WM=16, WN=64
      f32x4 acc[4];
#pragma unroll
      for (int j = 0; j < 4; ++j) acc[j] = 0.f;

      for (int k0 = 0; k0 < 512; k0 += 64) {
        __syncthreads();
        {
          int row = tid >> 3, cc = tid & 7, c = cc ^ (row & 7);
          gload_lds16(Acat + (size_t)(b0 + row) * 1280 + 768 + k0 + c * 8, sA + tid * 8);
        }
#pragma unroll
        for (int j = 0; j < 4; ++j) {
          int idx = j * 256 + tid, row = idx >> 3, cc = idx & 7, c = cc ^ (row & 7);
          gload_lds16(Whcatb + (size_t)(n0 + row) * 512 + k0 + c * 8, sB + idx * 8);
        }
        __syncthreads();
#pragma unroll
        for (int ks = 0; ks < 2; ++ks) {
          u16x8 av, bv[4];
          {
            int row = wr * 16 + l15;
            int ch = row * 8 + ((ks * 4 + lhi) ^ (row & 7));
            av = *(const u16x8*)(sA + ch * 8);
          }
#pragma unroll
          for (int ni = 0; ni < 4; ++ni) {
            int row = wc * 64 + ni * 16 + l15;
            int ch = row * 8 + ((ks * 4 + lhi) ^ (row & 7));
            bv[ni] = *(const u16x8*)(sB + ch * 8);
          }
#pragma unroll
          for (int ni = 0; ni < 4; ++ni) acc[ni] = mfma_bf16(av, bv[ni], acc[ni]);
        }
      }
      asm volatile("s_nop 7\ns_nop 7\ns_nop 7");
#pragma unroll
      for (int ni = 0; ni < 4; ++ni) {
        int col = n0 + (wave & 1) * 64 + ni * 16 + l15;
        int rowg = b0 + (wave >> 1) * 16 + lhi * 4;
        if (col < 512) {
          float bvv = b_h2h[col];
#pragma unroll
          for (int r = 0; r < 4; ++r)
            hpbuf[(size_t)(rowg + r) * 512 + col] = acc[ni][r] + bvv;
        } else {
#pragma unroll
          for (int r = 0; r < 4; ++r)
            ghbuf[(size_t)(rowg + r) * 2048 + col - 512] = acc[ni][r];
        }
      }
    }
    grid.sync();

    // ---------- phase A: attention (all 256 blocks, b = bid) ----------
    {
      int j0 = tid * 2;
      hpsp[j0 + (j0 >> 5)] = hpbuf[(size_t)bid * 512 + j0];
      hpsp[j0 + 1 + ((j0 + 1) >> 5)] = hpbuf[(size_t)bid * 512 + j0 + 1];
    }
    __syncthreads();
    {
      const int c16 = tid & 15;
      const int pc = (c16 + (c16 >> 2)) & 3;
      const int hbase = c16 * 33;
      float hpr[32], wsr[32];
#pragma unroll
      for (int j = 0; j < 32; ++j) {
        hpr[j] = hpsp[hbase + j];
        wsr[j] = wssp[hbase + j];
      }
#pragma unroll
      for (int tg = 0; tg < 4; ++tg) {
        int t = tg * 16 + (tid >> 4);
        float sacc = 0.f;
#pragma unroll
        for (int w = 0; w < 4; ++w) {
          u16x8 hv = *(const u16x8*)((char*)hp_lds + t * 1024 + c16 * 64 + ((w ^ pc) << 4));
#pragma unroll
          for (int j = 0; j < 8; ++j) {
            float x = bf2f(hv[j]) + hpr[w * 8 + j];
            sacc += fast_tanh(x) * wsr[w * 8 + j];
          }
        }
#pragma unroll
        for (int off = 8; off; off >>= 1) sacc += __shfl_xor(sacc, off, 16);
        if (c16 == 0) es[t] = sacc;
      }
      __syncthreads();
      if (tid < 64) {  // softmax over t
        float v = es[tid];
        float m = v;
#pragma unroll
        for (int o = 32; o; o >>= 1) m = fmaxf(m, __shfl_xor(m, o, 64));
        float p = __expf(v - m);
        float su = p;
#pragma unroll
        for (int o = 32; o; o >>= 1) su += __shfl_xor(su, o, 64);
        es[tid] = p / su;
      }
      __syncthreads();
      float c0 = 0.f, c1 = 0.f;
#pragma unroll 8
      for (int t = 0; t < 64; ++t) {
        u32 w2 = *(const u32*)((char*)bh_lds + t * 1024 + tid * 4);
        float a = es[t];
        c0 = fmaf(a, bf2f((u16)(w2 & 0xffffu)), c0);
        c1 = fmaf(a, bf2f((u16)(w2 >> 16)), c1);
      }
      u32 pk = (u32)f2bf(c0) | ((u32)f2bf(c1) << 16);
      *(u32*)(Acat + (size_t)bid * 1280 + tid * 2) = pk;
      int ci = text[bid * 26 + s];
      Acat[(size_t)bid * 1280 + 512 + tid] = embb[(size_t)ci * 256 + tid];
    }
    grid.sync();

    // ---------- phase B: gates_x GEMM + gh + bias + LSTM ----------
    if (bid < 128) {
      u16* sA = (u16*)gbuf;            // 32 x 64
      u16* sB = (u16*)(gbuf + 4096);   // 128 x 64
      const int jt = bid & 15;         // 32 j's
      const int b0 = (bid >> 4) * 32;  // 8 batch tiles
      const int wr = wave >> 1, wc = wave & 1;
      f32x4 acc[4];
#pragma unroll
      for (int j = 0; j < 4; ++j) acc[j] = 0.f;

      for (int k0 = 0; k0 < 768; k0 += 64) {
        __syncthreads();
        {
          int row = tid >> 3, cc = tid & 7, c = cc ^ (row & 7);
          gload_lds16(Acat + (size_t)(b0 + row) * 1280 + k0 + c * 8, sA + tid * 8);
        }
#pragma unroll
        for (int j = 0; j < 4; ++j) {
          int idx = j * 256 + tid, row = idx >> 3, cc = idx & 7, c = cc ^ (row & 7);
          int grow = (row >> 5) * 512 + jt * 32 + (row & 31);
          gload_lds16(Wihb + (size_t)grow * 768 + k0 + c * 8, sB + idx * 8);
        }
        __syncthreads();
#pragma unroll
        for (int ks = 0; ks < 2; ++ks) {
          u16x8 av, bv[4];
          {
            int row = wr * 16 + l15;
            int ch = row * 8 + ((ks * 4 + lhi) ^ (row & 7));
            av = *(const u16x8*)(sA + ch * 8);
          }
#pragma unroll
          for (int ni = 0; ni < 4; ++ni) {
            int row = wc * 64 + ni * 16 + l15;
            int ch = row * 8 + ((ks * 4 + lhi) ^ (row & 7));
            bv[ni] = *(const u16x8*)(sB + ch * 8);
          }
#pragma unroll
          for (int ni = 0; ni < 4; ++ni) acc[ni] = mfma_bf16(av, bv[ni], acc[ni]);
        }
      }
      asm volatile("s_nop 7\ns_nop 7\ns_nop 7");
      __syncthreads();                          // staging reads done -> reuse LDS
      float (*gsm)[132] = (float(*)[132])gbuf;  // 32 x 132 f32 = 16.9 KB
#pragma unroll
      for (int ni = 0; ni < 4; ++ni) {
        int col = wc * 64 + ni * 16 + l15;
        int row = wr * 16 + lhi * 4;
#pragma unroll
        for (int r = 0; r < 4; ++r) gsm[row + r][col] = acc[ni][r];
      }
      __syncthreads();
      {  // LSTM: thread owns bl = tid>>3, 4 j's at jl0 = (tid&7)*4
        const int bl = tid >> 3, jl0 = (tid & 7) * 4;
        const int b = b0 + bl;
        const int jg0 = jt * 32 + jl0;
        const float* gh = ghbuf + (size_t)b * 2048;
        float cn[4];
        u16 hb[4];
#pragma unroll
        for (int q = 0; q < 4; ++q) {
          int jl = jl0 + q, j = jg0 + q;
          float gi = gsm[bl][jl]      + gh[j]        + biascat[j];
          float gf = gsm[bl][32 + jl] + gh[512 + j]  + biascat[512 + j];
          float gg = gsm[bl][64 + jl] + gh[1024 + j] + biascat[1024 + j];
          float go = gsm[bl][96 + jl] + gh[1536 + j] + biascat[1536 + j];
          float c = fast_sig(gf) * cst[(size_t)b * 512 + j] + fast_sig(gi) * fast_tanh(gg);
          cn[q] = c;
          hb[q] = f2bf(fast_sig(go) * fast_tanh(c));
        }
        *(f32x4*)(cst + (size_t)b * 512 + jg0) = *(f32x4*)cn;
        *(u16x4*)(Acat + (size_t)b * 1280 + 768 + jg0) = *(u16x4*)hb;
        *(u16x4*)(hsb + (size_t)(b * 26 + s) * 512 + jg0) = *(u16x4*)hb;
      }
    }
    grid.sync();
  }
}

// ---------------- launch ----------------
extern "C" void kernel_launch(void* const* d_in, const int* in_sizes, int n_in,
                              void* d_out, int out_size, void* d_ws, size_t ws_size,
                              hipStream_t stream) {
  const float* batch_H = (const float*)d_in[0];
  const int*   text    = (const int*)d_in[1];
  const float* W_i2h   = (const float*)d_in[2];
  const float* W_h2h   = (const float*)d_in[3];
  const float* b_h2h   = (const float*)d_in[4];
  const float* w_score = (const float*)d_in[5];
  const float* W_ih    = (const float*)d_in[6];
  const float* W_hh    = (const float*)d_in[7];
  const float* b_ih    = (const float*)d_in[8];
  const float* b_hh    = (const float*)d_in[9];
  const float* emb     = (const float*)d_in[10];
  const float* W_gen   = (const float*)d_in[11];
  const float* b_gen   = (const float*)d_in[12];
  float* out = (float*)d_out;

  // Big bf16 scratch at the front of d_out (fully overwritten by the final GEMM,
  // which reads only hsb/Wgenb).
  u16* bHb   = (u16*)d_out;          // 16 MB
  u16* Hproj = bHb + 8388608;        // 16 MB

  char* w = (char*)d_ws;
  auto alloc = [&](size_t bytes) {
    char* p = w;
    w += (bytes + 255) & ~(size_t)255;
    return p;
  };
  u16*   Wi2hb   = (u16*)alloc(512ull * 512 * 2);
  u16*   Whcatb  = (u16*)alloc(2560ull * 512 * 2);   // [W_h2h ; W_hh]
  u16*   Wihb    = (u16*)alloc(2048ull * 768 * 2);
  u16*   Wgenb   = (u16*)alloc(6656ull * 512 * 2);
  u16*   embb    = (u16*)alloc(6624ull * 256 * 2);
  float* biascat = (float*)alloc(2048ull * 4);
  u16*   Acat    = (u16*)alloc(256ull * 1280 * 2);   // [ctx(512) | ce(256) | h(512)]
  float* cst     = (float*)alloc(256ull * 512 * 4);
  float* hpbuf   = (float*)alloc(256ull * 512 * 4);
  float* ghbuf   = (float*)alloc(256ull * 2048 * 4);
  u16*   hsb     = (u16*)alloc(6656ull * 512 * 2);

  // 1) fused prep (all conversions + packing + zero Acat/cst)
  k_prep<<<16538, 256, 0, stream>>>(batch_H, W_i2h, emb, W_ih, W_h2h, W_hh, W_gen,
                                    b_ih, b_hh, bHb, Wi2hb, embb, Wihb, Whcatb,
                                    Wgenb, biascat, Acat, cst);

  // 2) Hproj = batch_H @ W_i2h^T -> bf16
  gemm_bt<128, 128, 64, 64, 2><<<dim3(4, 128), 256, 0, stream>>>(
      bHb, 512, Wi2hb, 512, nullptr, nullptr, Hproj, 512, 512, 512);

  // 3) persistent cooperative 26-step recurrence
  {
    void* kargs[] = {(void*)&Hproj, (void*)&bHb,   (void*)&Whcatb, (void*)&Wihb,
                     (void*)&b_h2h, (void*)&w_score, (void*)&embb, (void*)&text,
                     (void*)&Acat,  (void*)&hpbuf, (void*)&ghbuf,  (void*)&cst,
                     (void*)&hsb,   (void*)&biascat};
    hipLaunchCooperativeKernel(reinterpret_cast<void*>(coop_loop), dim3(256), dim3(256),
                               kargs, 0, stream);
  }

  // 4) probs = hs @ W_gen^T + b_gen -> f32 out (M=6656, N=6624, K=512)
  gemm_bt<128, 128, 64, 64, 1><<<dim3(52, 52), 256, 0, stream>>>(
      hsb, 512, Wgenb, 512, b_gen, out, nullptr, 6624, 6624, 512);

  (void)in_sizes; (void)n_in; (void)out_size; (void)ws_size;
}

// Round 5
// 902.103 us; speedup vs baseline: 3.3205x; 3.3205x over previous
//
#include <hip/hip_runtime.h>

typedef unsigned short u16;
typedef unsigned int   u32;
typedef __attribute__((ext_vector_type(4))) float f32x4;
typedef __attribute__((ext_vector_type(8))) u16   u16x8;
typedef __attribute__((ext_vector_type(4))) u16   u16x4;
typedef __attribute__((ext_vector_type(4))) u32   u32x4;

// ---------------- helpers ----------------
__device__ __forceinline__ u16 f2bf(float x) {
  u32 u = __builtin_bit_cast(u32, x);
  u = (u + 0x7fffu + ((u >> 16) & 1u)) >> 16;
  return (u16)u;
}
__device__ __forceinline__ float bf2f(u16 h) {
  return __builtin_bit_cast(float, (u32)h << 16);
}
__device__ __forceinline__ float fast_sig(float x) { return 1.f / (1.f + __expf(-x)); }
__device__ __forceinline__ float fast_tanh(float x) {
  float e = __expf(2.f * x);
  return 1.f - 2.f / (e + 1.f);
}

__device__ __forceinline__ f32x4 mfma_bf16(u16x8 a, u16x8 b, f32x4 c) {
  asm volatile("v_mfma_f32_16x16x32_bf16 %0, %1, %2, %0" : "+v"(c) : "v"(a), "v"(b));
  return c;
}

__device__ __forceinline__ void gload_lds16(const void* g, void* l) {
  __builtin_amdgcn_global_load_lds(
      (__attribute__((address_space(1))) u32*)g,
      (__attribute__((address_space(3))) u32*)l, 16, 0, 0);
}

// ---------------- fused prep: all conversions + packing + zeroing, one kernel ----------------
__device__ __forceinline__ void conv4(const float* __restrict__ s, u16* __restrict__ d, int i) {
  f32x4 v = *(const f32x4*)(s + i);
  u16x4 o;
  o.x = f2bf(v.x); o.y = f2bf(v.y); o.z = f2bf(v.z); o.w = f2bf(v.w);
  *(u16x4*)(d + i) = o;
}

__global__ __launch_bounds__(256) void k_prep(
    const float* __restrict__ batch_H, const float* __restrict__ W_i2h,
    const float* __restrict__ emb, const float* __restrict__ W_ih,
    const float* __restrict__ W_h2h, const float* __restrict__ W_hh,
    const float* __restrict__ W_gen, const float* __restrict__ b_ih,
    const float* __restrict__ b_hh,
    u16* __restrict__ bHb, u16* __restrict__ Wi2hb, u16* __restrict__ embb,
    u16* __restrict__ Wihb, u16* __restrict__ Whcatb, u16* __restrict__ Wgenb,
    float* __restrict__ biascat, u16* __restrict__ Acat, float* __restrict__ cst) {
  const u32 u = blockIdx.x * 256 + threadIdx.x;
  if (u < 2097152u) { conv4(batch_H, bHb, u * 4); return; }
  if (u < 2162688u) { conv4(W_i2h, Wi2hb, (u - 2097152u) * 4); return; }
  if (u < 2586624u) { conv4(emb, embb, (u - 2162688u) * 4); return; }
  if (u < 2979840u) { conv4(W_ih, Wihb, (u - 2586624u) * 4); return; }
  if (u < 3307520u) {  // Whcat = [W_h2h ; W_hh], 2560 x 512
    int i = (u - 2979840u) * 4;
    int r = i >> 9, c = i & 511;
    const float* src = (r < 512) ? (W_h2h + (size_t)r * 512 + c)
                                 : (W_hh + (size_t)(r - 512) * 512 + c);
    f32x4 v = *(const f32x4*)src;
    u16x4 o;
    o.x = f2bf(v.x); o.y = f2bf(v.y); o.z = f2bf(v.z); o.w = f2bf(v.w);
    *(u16x4*)(Whcatb + i) = o;
    return;
  }
  if (u < 4159488u) {  // Wgen padded to 6656 rows
    int i = (u - 3307520u) * 4;
    int r = i >> 9;
    if (r < 6624) conv4(W_gen, Wgenb, i);
    else *(u16x4*)(Wgenb + i) = (u16x4){0, 0, 0, 0};
    return;
  }
  if (u < 4160000u) {  // biascat
    int j = (u - 4159488u) * 4;
    f32x4 a = *(const f32x4*)(b_ih + j), b = *(const f32x4*)(b_hh + j);
    f32x4 r = {a.x + b.x, a.y + b.y, a.z + b.z, a.w + b.w};
    *(f32x4*)(biascat + j) = r;
    return;
  }
  if (u < 4200960u) {  // zero Acat (16B units)
    *(u32x4*)((char*)Acat + (size_t)(u - 4160000u) * 16) = (u32x4){0, 0, 0, 0};
    return;
  }
  if (u < 4233728u) {  // zero cst
    *(u32x4*)((char*)cst + (size_t)(u - 4200960u) * 16) = (u32x4){0, 0, 0, 0};
    return;
  }
}

// ---------------- big GEMM: C[M,N] = A[M,K] * B[N,K]^T (+bias), BK=32 ----------------
// OUT_MODE: 1 = f32 + bias, 2 = bf16 (no bias)
template <int BM, int BN, int WM, int WN, int OUT_MODE>
__global__ __launch_bounds__(256) void gemm_bt(const u16* __restrict__ A, int lda,
                                               const u16* __restrict__ B, int ldb,
                                               const float* __restrict__ bias,
                                               float* __restrict__ Cf, u16* __restrict__ Cb,
                                               int ldc, int Nreal, int K) {
  static_assert((BM / WM) * (BN / WN) == 4, "4 waves");
  constexpr int FM = WM / 16, FN = WN / 16;
  constexpr int NWC = BN / WN;
  constexpr int CHA = (BM * 4) / 256, CHB = (BN * 4) / 256;
  __shared__ __align__(16) u16 sA[BM * 32];
  __shared__ __align__(16) u16 sB[BN * 32];
  const int tid = threadIdx.x;
  const int lane = tid & 63, wave = tid >> 6;
  const int wr = wave / NWC, wc = wave % NWC;
  const int l15 = lane & 15, lhi = lane >> 4;
  const int m0 = blockIdx.y * BM, n0 = blockIdx.x * BN;

  f32x4 acc[FM][FN];
#pragma unroll
  for (int i = 0; i < FM; ++i)
#pragma unroll
    for (int j = 0; j < FN; ++j) acc[i][j] = 0.f;

  for (int k0 = 0; k0 < K; k0 += 32) {
    __syncthreads();
#pragma unroll
    for (int j = 0; j < CHA; ++j) {
      int idx = j * 256 + tid;
      int row = idx >> 2, cc = idx & 3;
      int c = cc ^ ((row >> 1) & 3);
      gload_lds16(A + (size_t)(m0 + row) * lda + (k0 + c * 8), sA + idx * 8);
    }
#pragma unroll
    for (int j = 0; j < CHB; ++j) {
      int idx = j * 256 + tid;
      int row = idx >> 2, cc = idx & 3;
      int c = cc ^ ((row >> 1) & 3);
      gload_lds16(B + (size_t)(n0 + row) * ldb + (k0 + c * 8), sB + idx * 8);
    }
    __syncthreads();

    u16x8 av[FM], bv[FN];
#pragma unroll
    for (int mi = 0; mi < FM; ++mi) {
      int row = wr * WM + mi * 16 + l15;
      int ch = row * 4 + (lhi ^ ((row >> 1) & 3));
      av[mi] = *(const u16x8*)(sA + ch * 8);
    }
#pragma unroll
    for (int ni = 0; ni < FN; ++ni) {
      int row = wc * WN + ni * 16 + l15;
      int ch = row * 4 + (lhi ^ ((row >> 1) & 3));
      bv[ni] = *(const u16x8*)(sB + ch * 8);
    }
#pragma unroll
    for (int mi = 0; mi < FM; ++mi)
#pragma unroll
      for (int ni = 0; ni < FN; ++ni) acc[mi][ni] = mfma_bf16(av[mi], bv[ni], acc[mi][ni]);
  }

  asm volatile("s_nop 7\ns_nop 7\ns_nop 7");  // MFMA->VALU hazard guard

#pragma unroll
  for (int mi = 0; mi < FM; ++mi) {
#pragma unroll
    for (int ni = 0; ni < FN; ++ni) {
      int col = n0 + wc * WN + ni * 16 + l15;
      if (col < Nreal) {
        float bvv = (OUT_MODE == 1) ? bias[col] : 0.f;
#pragma unroll
        for (int r = 0; r < 4; ++r) {
          int row = m0 + wr * WM + mi * 16 + lhi * 4 + r;
          float v = acc[mi][ni][r] + bvv;
          if (OUT_MODE == 2)
            Cb[(size_t)row * ldc + col] = f2bf(v);
          else
            Cf[(size_t)row * ldc + col] = v;
        }
      }
    }
  }
}

// ---------------- kA: hp + gh GEMM ----------------
// [hp|gh][256, 2560] = h[256,512] @ [W_h2h;W_hh]^T ; hp gets +b_h2h.
// grid 160: b0 = (bid/20)*32, n0 = (bid%20)*128. BM=32, BN=128, BK=64.
__global__ __launch_bounds__(256) void kA_hpgh(const u16* __restrict__ Acat,
                                               const u16* __restrict__ Whcatb,
                                               const float* __restrict__ b_h2h,
                                               float* __restrict__ hpbuf,
                                               float* __restrict__ ghbuf) {
  __shared__ __align__(16) u16 sA[32 * 64];
  __shared__ __align__(16) u16 sB[128 * 64];
  const int tid = threadIdx.x;
  const int lane = tid & 63, wave = tid >> 6;
  const int wr = wave >> 1, wc = wave & 1;  // WM=16, WN=64
  const int l15 = lane & 15, lhi = lane >> 4;
  const int b0 = ((int)blockIdx.x / 20) * 32, n0 = ((int)blockIdx.x % 20) * 128;

  f32x4 acc[4];
#pragma unroll
  for (int j = 0; j < 4; ++j) acc[j] = 0.f;

  for (int k0 = 0; k0 < 512; k0 += 64) {
    __syncthreads();
    {
      int row = tid >> 3, cc = tid & 7, c = cc ^ (row & 7);
      gload_lds16(Acat + (size_t)(b0 + row) * 1280 + 768 + k0 + c * 8, sA + tid * 8);
    }
#pragma unroll
    for (int j = 0; j < 4; ++j) {
      int idx = j * 256 + tid, row = idx >> 3, cc = idx & 7, c = cc ^ (row & 7);
      gload_lds16(Whcatb + (size_t)(n0 + row) * 512 + k0 + c * 8, sB + idx * 8);
    }
    __syncthreads();
#pragma unroll
    for (int ks = 0; ks < 2; ++ks) {
      u16x8 av, bv[4];
      {
        int row = wr * 16 + l15;
        int ch = row * 8 + ((ks * 4 + lhi) ^ (row & 7));
        av = *(const u16x8*)(sA + ch * 8);
      }
#pragma unroll
      for (int ni = 0; ni < 4; ++ni) {
        int row = wc * 64 + ni * 16 + l15;
        int ch = row * 8 + ((ks * 4 + lhi) ^ (row & 7));
        bv[ni] = *(const u16x8*)(sB + ch * 8);
      }
#pragma unroll
      for (int ni = 0; ni < 4; ++ni) acc[ni] = mfma_bf16(av, bv[ni], acc[ni]);
    }
  }
  asm volatile("s_nop 7\ns_nop 7\ns_nop 7");
#pragma unroll
  for (int ni = 0; ni < 4; ++ni) {
    int col = n0 + wc * 64 + ni * 16 + l15;
    int rowg = b0 + wr * 16 + lhi * 4;
    if (col < 512) {
      float bvv = b_h2h[col];
#pragma unroll
      for (int r = 0; r < 4; ++r)
        hpbuf[(size_t)(rowg + r) * 512 + col] = acc[ni][r] + bvv;
    } else {
#pragma unroll
      for (int r = 0; r < 4; ++r)
        ghbuf[(size_t)(rowg + r) * 2048 + col - 512] = acc[ni][r];
    }
  }
}

// ---------------- kB: attention (reads hpbuf) ----------------
// block b: e[t] = sum_h tanh(Hproj[b,t,h] + hp[b,h]) * w_score[h]; alpha = softmax;
// ctx = sum_t alpha[t]*bH[b,t,:]; writes ctx|ce into Acat.
__global__ __launch_bounds__(256) void kB_attn(const u16* __restrict__ Hproj,
                                               const float* __restrict__ hpbuf,
                                               const float* __restrict__ wsc,
                                               const u16* __restrict__ bh,
                                               const u16* __restrict__ embb,
                                               const int* __restrict__ text, int step,
                                               u16* __restrict__ Acat) {
  const int b = blockIdx.x, tid = threadIdx.x;
  __shared__ float hpsp[528];  // padded: j -> j + (j>>5)
  __shared__ float wssp[528];
  __shared__ float es[64];

  {
    int j0 = tid * 2;
    hpsp[j0 + (j0 >> 5)] = hpbuf[(size_t)b * 512 + j0];
    hpsp[j0 + 1 + ((j0 + 1) >> 5)] = hpbuf[(size_t)b * 512 + j0 + 1];
    int pi = j0 + (j0 >> 5);
    wssp[pi] = wsc[j0];
    wssp[pi + 1] = wsc[j0 + 1];
  }
  __syncthreads();

  const int ch16 = tid & 15;
  const int hbase = ch16 * 33;
  const int hc = ch16 * 32;
  float hpr[32], wsr[32];
#pragma unroll
  for (int j = 0; j < 32; ++j) {
    hpr[j] = hpsp[hbase + j];
    wsr[j] = wssp[hbase + j];
  }
#pragma unroll
  for (int tg = 0; tg < 4; ++tg) {
    int t = tg * 16 + (tid >> 4);
    const u16* hr = Hproj + (size_t)(b * 64 + t) * 512 + hc;
    float s = 0.f;
#pragma unroll
    for (int jo = 0; jo < 32; jo += 8) {
      u16x8 hv = *(const u16x8*)(hr + jo);
#pragma unroll
      for (int j = 0; j < 8; ++j) {
        float x = bf2f(hv[j]) + hpr[jo + j];
        s += fast_tanh(x) * wsr[jo + j];
      }
    }
#pragma unroll
    for (int off = 8; off; off >>= 1) s += __shfl_xor(s, off, 16);
    if (ch16 == 0) es[t] = s;
  }
  __syncthreads();
  if (tid < 64) {  // softmax over t
    float v = es[tid];
    float m = v;
#pragma unroll
    for (int o = 32; o; o >>= 1) m = fmaxf(m, __shfl_xor(m, o, 64));
    float p = __expf(v - m);
    float su = p;
#pragma unroll
    for (int o = 32; o; o >>= 1) su += __shfl_xor(su, o, 64);
    es[tid] = p / su;
  }
  __syncthreads();
  const u16* base = bh + (size_t)b * 32768 + tid * 2;
  float c0 = 0.f, c1 = 0.f;
#pragma unroll 8
  for (int t = 0; t < 64; ++t) {
    u32 w = *(const u32*)(base + t * 512);
    float a = es[t];
    c0 = fmaf(a, bf2f((u16)(w & 0xffffu)), c0);
    c1 = fmaf(a, bf2f((u16)(w >> 16)), c1);
  }
  u32 pk = (u32)f2bf(c0) | ((u32)f2bf(c1) << 16);
  *(u32*)(Acat + (size_t)b * 1280 + tid * 2) = pk;
  int ci = text[b * 26 + step];
  Acat[(size_t)b * 1280 + 512 + tid] = embb[(size_t)ci * 256 + tid];
}

// ---------------- kC: gates_x GEMM (K=768) + gh + bias + LSTM ----------------
// grid (16, 8): jt = 32-wide j-tile (x4 gate segs -> BN=128), b0 = 32-wide batch tile.
__global__ __launch_bounds__(256) void kC_gates_lstm(const u16* __restrict__ Acat_ro,
                                                     const u16* __restrict__ Wihb,
                                                     const float* __restrict__ biascat,
                                                     const float* __restrict__ ghbuf,
                                                     float* __restrict__ cst,
                                                     u16* __restrict__ Acat,
                                                     u16* __restrict__ hsb, int step) {
  __shared__ __align__(16) char smem[20480];  // sA 4KB + sB 16KB; reused: gsm 32x132 f32
  u16* sA = (u16*)smem;           // 32 x 64
  u16* sB = (u16*)(smem + 4096);  // 128 x 64
  const int tid = threadIdx.x;
  const int lane = tid & 63, wave = tid >> 6;
  const int wr = wave >> 1, wc = wave & 1;  // WM=16, WN=64
  const int l15 = lane & 15, lhi = lane >> 4;
  const int jt = blockIdx.x;
  const int b0 = blockIdx.y * 32;

  f32x4 acc[4];
#pragma unroll
  for (int j = 0; j < 4; ++j) acc[j] = 0.f;

  for (int k0 = 0; k0 < 768; k0 += 64) {
    __syncthreads();
    {
      int row = tid >> 3, cc = tid & 7, c = cc ^ (row & 7);
      gload_lds16(Acat_ro + (size_t)(b0 + row) * 1280 + k0 + c * 8, sA + tid * 8);
    }
#pragma unroll
    for (int j = 0; j < 4; ++j) {
      int idx = j * 256 + tid, row = idx >> 3, cc = idx & 7, c = cc ^ (row & 7);
      int grow = (row >> 5) * 512 + jt * 32 + (row & 31);
      gload_lds16(Wihb + (size_t)grow * 768 + k0 + c * 8, sB + idx * 8);
    }
    __syncthreads();

#pragma unroll
    for (int ks = 0; ks < 2; ++ks) {
      u16x8 av, bv[4];
      {
        int row = wr * 16 + l15;
        int ch = row * 8 + ((ks * 4 + lhi) ^ (row & 7));
        av = *(const u16x8*)(sA + ch * 8);
      }
#pragma unroll
      for (int ni = 0; ni < 4; ++ni) {
        int row = wc * 64 + ni * 16 + l15;
        int ch = row * 8 + ((ks * 4 + lhi) ^ (row & 7));
        bv[ni] = *(const u16x8*)(sB + ch * 8);
      }
#pragma unroll
      for (int ni = 0; ni < 4; ++ni) acc[ni] = mfma_bf16(av, bv[ni], acc[ni]);
    }
  }

  asm volatile("s_nop 7\ns_nop 7\ns_nop 7");  // MFMA->VALU hazard guard
  __syncthreads();                            // staging reads done -> reuse LDS
  float (*gsm)[132] = (float(*)[132])smem;    // 32 x 132 f32 = 16.9 KB
#pragma unroll
  for (int ni = 0; ni < 4; ++ni) {
    int col = wc * 64 + ni * 16 + l15;
    int row = wr * 16 + lhi * 4;
#pragma unroll
    for (int r = 0; r < 4; ++r) gsm[row + r][col] = acc[ni][r];
  }
  __syncthreads();

  {  // LSTM: thread owns bl = tid>>3, 4 j's at jl0 = (tid&7)*4
    const int bl = tid >> 3, jl0 = (tid & 7) * 4;
    const int b = b0 + bl;
    const int jg0 = jt * 32 + jl0;
    const float* gh = ghbuf + (size_t)b * 2048;
    float cn[4];
    u16 hb[4];
#pragma unroll
    for (int q = 0; q < 4; ++q) {
      int jl = jl0 + q, j = jg0 + q;
      float gi = gsm[bl][jl]      + gh[j]        + biascat[j];
      float gf = gsm[bl][32 + jl] + gh[512 + j]  + biascat[512 + j];
      float gg = gsm[bl][64 + jl] + gh[1024 + j] + biascat[1024 + j];
      float go = gsm[bl][96 + jl] + gh[1536 + j] + biascat[1536 + j];
      float c = fast_sig(gf) * cst[(size_t)b * 512 + j] + fast_sig(gi) * fast_tanh(gg);
      cn[q] = c;
      hb[q] = f2bf(fast_sig(go) * fast_tanh(c));
    }
    *(f32x4*)(cst + (size_t)b * 512 + jg0) = *(f32x4*)cn;
    *(u16x4*)(Acat + (size_t)b * 1280 + 768 + jg0) = *(u16x4*)hb;
    *(u16x4*)(hsb + (size_t)(b * 26 + step) * 512 + jg0) = *(u16x4*)hb;
  }
}

// ---------------- launch ----------------
extern "C" void kernel_launch(void* const* d_in, const int* in_sizes, int n_in,
                              void* d_out, int out_size, void* d_ws, size_t ws_size,
                              hipStream_t stream) {
  const float* batch_H = (const float*)d_in[0];
  const int*   text    = (const int*)d_in[1];
  const float* W_i2h   = (const float*)d_in[2];
  const float* W_h2h   = (const float*)d_in[3];
  const float* b_h2h   = (const float*)d_in[4];
  const float* w_score = (const float*)d_in[5];
  const float* W_ih    = (const float*)d_in[6];
  const float* W_hh    = (const float*)d_in[7];
  const float* b_ih    = (const float*)d_in[8];
  const float* b_hh    = (const float*)d_in[9];
  const float* emb     = (const float*)d_in[10];
  const float* W_gen   = (const float*)d_in[11];
  const float* b_gen   = (const float*)d_in[12];
  float* out = (float*)d_out;

  // Big bf16 scratch at the front of d_out (fully overwritten by the final GEMM,
  // which reads only hsb/Wgenb).
  u16* bHb   = (u16*)d_out;          // 16 MB
  u16* Hproj = bHb + 8388608;        // 16 MB

  char* w = (char*)d_ws;
  auto alloc = [&](size_t bytes) {
    char* p = w;
    w += (bytes + 255) & ~(size_t)255;
    return p;
  };
  u16*   Wi2hb   = (u16*)alloc(512ull * 512 * 2);
  u16*   Whcatb  = (u16*)alloc(2560ull * 512 * 2);   // [W_h2h ; W_hh]
  u16*   Wihb    = (u16*)alloc(2048ull * 768 * 2);
  u16*   Wgenb   = (u16*)alloc(6656ull * 512 * 2);
  u16*   embb    = (u16*)alloc(6624ull * 256 * 2);
  float* biascat = (float*)alloc(2048ull * 4);
  u16*   Acat    = (u16*)alloc(256ull * 1280 * 2);   // [ctx(512) | ce(256) | h(512)]
  float* cst     = (float*)alloc(256ull * 512 * 4);
  float* hpbuf   = (float*)alloc(256ull * 512 * 4);
  float* ghbuf   = (float*)alloc(256ull * 2048 * 4);
  u16*   hsb     = (u16*)alloc(6656ull * 512 * 2);

  // 1) fused prep (all conversions + packing + zero Acat/cst)
  k_prep<<<16538, 256, 0, stream>>>(batch_H, W_i2h, emb, W_ih, W_h2h, W_hh, W_gen,
                                    b_ih, b_hh, bHb, Wi2hb, embb, Wihb, Whcatb,
                                    Wgenb, biascat, Acat, cst);

  // 2) Hproj = batch_H @ W_i2h^T -> bf16
  gemm_bt<128, 128, 64, 64, 2><<<dim3(4, 128), 256, 0, stream>>>(
      bHb, 512, Wi2hb, 512, nullptr, nullptr, Hproj, 512, 512, 512);

  // 3) recurrence: 3 small kernels per step
  for (int s = 0; s < 26; ++s) {
    kA_hpgh<<<160, 256, 0, stream>>>(Acat, Whcatb, b_h2h, hpbuf, ghbuf);
    kB_attn<<<256, 256, 0, stream>>>(Hproj, hpbuf, w_score, bHb, embb, text, s, Acat);
    kC_gates_lstm<<<dim3(16, 8), 256, 0, stream>>>(Acat, Wihb, biascat, ghbuf, cst,
                                                   Acat, hsb, s);
  }

  // 4) probs = hs @ W_gen^T + b_gen -> f32 out (M=6656, N=6624, K=512)
  gemm_bt<128, 128, 64, 64, 1><<<dim3(52, 52), 256, 0, stream>>>(
      hsb, 512, Wgenb, 512, b_gen, out, nullptr, 6624, 6624, 512);

  (void)in_sizes; (void)n_in; (void)out_size; (void)ws_size;
}

// Round 6
// 823.730 us; speedup vs baseline: 3.6364x; 1.0951x over previous
//
#include <hip/hip_runtime.h>

typedef unsigned short u16;
typedef unsigned int   u32;
typedef __attribute__((ext_vector_type(4))) float f32x4;
typedef __attribute__((ext_vector_type(8))) u16   u16x8;
typedef __attribute__((ext_vector_type(4))) u16   u16x4;
typedef __attribute__((ext_vector_type(4))) u32   u32x4;

// ---------------- helpers ----------------
__device__ __forceinline__ u16 f2bf(float x) {
  u32 u = __builtin_bit_cast(u32, x);
  u = (u + 0x7fffu + ((u >> 16) & 1u)) >> 16;
  return (u16)u;
}
__device__ __forceinline__ float bf2f(u16 h) {
  return __builtin_bit_cast(float, (u32)h << 16);
}
__device__ __forceinline__ float fast_sig(float x) { return 1.f / (1.f + __expf(-x)); }
__device__ __forceinline__ float fast_tanh(float x) {
  float e = __expf(2.f * x);
  return 1.f - 2.f / (e + 1.f);
}

__device__ __forceinline__ f32x4 mfma_bf16(u16x8 a, u16x8 b, f32x4 c) {
  asm volatile("v_mfma_f32_16x16x32_bf16 %0, %1, %2, %0" : "+v"(c) : "v"(a), "v"(b));
  return c;
}

__device__ __forceinline__ void gload_lds16(const void* g, void* l) {
  __builtin_amdgcn_global_load_lds(
      (__attribute__((address_space(1))) u32*)g,
      (__attribute__((address_space(3))) u32*)l, 16, 0, 0);
}

// ---------------- fused prep ----------------
__device__ __forceinline__ void conv4(const float* __restrict__ s, u16* __restrict__ d, int i) {
  f32x4 v = *(const f32x4*)(s + i);
  u16x4 o;
  o.x = f2bf(v.x); o.y = f2bf(v.y); o.z = f2bf(v.z); o.w = f2bf(v.w);
  *(u16x4*)(d + i) = o;
}

__global__ __launch_bounds__(256) void k_prep(
    const float* __restrict__ batch_H, const float* __restrict__ W_i2h,
    const float* __restrict__ emb, const float* __restrict__ W_ih,
    const float* __restrict__ W_h2h, const float* __restrict__ W_hh,
    const float* __restrict__ W_gen, const float* __restrict__ b_ih,
    const float* __restrict__ b_hh,
    u16* __restrict__ bHb, u16* __restrict__ Wi2hb, u16* __restrict__ embb,
    u16* __restrict__ Wctxb, u16* __restrict__ Wceb, u16* __restrict__ Whcatb,
    u16* __restrict__ Wgenb, float* __restrict__ biascat,
    u16* __restrict__ hb, float* __restrict__ cst) {
  const u32 u = blockIdx.x * 256 + threadIdx.x;
  if (u < 2097152u) { conv4(batch_H, bHb, u * 4); return; }
  if (u < 2162688u) { conv4(W_i2h, Wi2hb, (u - 2097152u) * 4); return; }
  if (u < 2586624u) { conv4(emb, embb, (u - 2162688u) * 4); return; }
  if (u < 2588672u) {  // zero emb pad rows 6624..6655
    *(u16x4*)(embb + 1695744u + (u - 2586624u) * 4) = (u16x4){0, 0, 0, 0};
    return;
  }
  if (u < 2850816u) {  // Wctx = W_ih[:, 0:512]
    int i = (u - 2588672u) * 4;
    int r = i >> 9, c = i & 511;
    f32x4 v = *(const f32x4*)(W_ih + (size_t)r * 768 + c);
    u16x4 o;
    o.x = f2bf(v.x); o.y = f2bf(v.y); o.z = f2bf(v.z); o.w = f2bf(v.w);
    *(u16x4*)(Wctxb + i) = o;
    return;
  }
  if (u < 2981888u) {  // Wce = W_ih[:, 512:768]
    int i = (u - 2850816u) * 4;
    int r = i >> 8, c = i & 255;
    f32x4 v = *(const f32x4*)(W_ih + (size_t)r * 768 + 512 + c);
    u16x4 o;
    o.x = f2bf(v.x); o.y = f2bf(v.y); o.z = f2bf(v.z); o.w = f2bf(v.w);
    *(u16x4*)(Wceb + i) = o;
    return;
  }
  if (u < 3309568u) {  // Whcat = [W_h2h ; W_hh], 2560 x 512
    int i = (u - 2981888u) * 4;
    int r = i >> 9, c = i & 511;
    const float* src = (r < 512) ? (W_h2h + (size_t)r * 512 + c)
                                 : (W_hh + (size_t)(r - 512) * 512 + c);
    f32x4 v = *(const f32x4*)src;
    u16x4 o;
    o.x = f2bf(v.x); o.y = f2bf(v.y); o.z = f2bf(v.z); o.w = f2bf(v.w);
    *(u16x4*)(Whcatb + i) = o;
    return;
  }
  if (u < 4161536u) {  // Wgen padded to 6656 rows
    int i = (u - 3309568u) * 4;
    int r = i >> 9;
    if (r < 6624) conv4(W_gen, Wgenb, i);
    else *(u16x4*)(Wgenb + i) = (u16x4){0, 0, 0, 0};
    return;
  }
  if (u < 4162048u) {  // biascat
    int j = (u - 4161536u) * 4;
    f32x4 a = *(const f32x4*)(b_ih + j), b = *(const f32x4*)(b_hh + j);
    f32x4 r = {a.x + b.x, a.y + b.y, a.z + b.z, a.w + b.w};
    *(f32x4*)(biascat + j) = r;
    return;
  }
  if (u < 4178432u) {  // zero hb (h0 = 0), 16B units
    *(u32x4*)((char*)hb + (size_t)(u - 4162048u) * 16) = (u32x4){0, 0, 0, 0};
    return;
  }
  if (u < 4211200u) {  // zero cst
    *(u32x4*)((char*)cst + (size_t)(u - 4178432u) * 16) = (u32x4){0, 0, 0, 0};
    return;
  }
}

// ---------------- big GEMM: C[M,N] = A[M,K] * B[N,K]^T (+bias), BK=32 ----------------
// OUT_MODE: 1 = f32 + bias, 2 = bf16 (no bias)
template <int BM, int BN, int WM, int WN, int OUT_MODE>
__global__ __launch_bounds__(256) void gemm_bt(const u16* __restrict__ A, int lda,
                                               const u16* __restrict__ B, int ldb,
                                               const float* __restrict__ bias,
                                               float* __restrict__ Cf, u16* __restrict__ Cb,
                                               int ldc, int Nreal, int K) {
  static_assert((BM / WM) * (BN / WN) == 4, "4 waves");
  constexpr int FM = WM / 16, FN = WN / 16;
  constexpr int NWC = BN / WN;
  constexpr int CHA = (BM * 4) / 256, CHB = (BN * 4) / 256;
  __shared__ __align__(16) u16 sA[BM * 32];
  __shared__ __align__(16) u16 sB[BN * 32];
  const int tid = threadIdx.x;
  const int lane = tid & 63, wave = tid >> 6;
  const int wr = wave / NWC, wc = wave % NWC;
  const int l15 = lane & 15, lhi = lane >> 4;
  const int m0 = blockIdx.y * BM, n0 = blockIdx.x * BN;

  f32x4 acc[FM][FN];
#pragma unroll
  for (int i = 0; i < FM; ++i)
#pragma unroll
    for (int j = 0; j < FN; ++j) acc[i][j] = 0.f;

  for (int k0 = 0; k0 < K; k0 += 32) {
    __syncthreads();
#pragma unroll
    for (int j = 0; j < CHA; ++j) {
      int idx = j * 256 + tid;
      int row = idx >> 2, cc = idx & 3;
      int c = cc ^ ((row >> 1) & 3);
      gload_lds16(A + (size_t)(m0 + row) * lda + (k0 + c * 8), sA + idx * 8);
    }
#pragma unroll
    for (int j = 0; j < CHB; ++j) {
      int idx = j * 256 + tid;
      int row = idx >> 2, cc = idx & 3;
      int c = cc ^ ((row >> 1) & 3);
      gload_lds16(B + (size_t)(n0 + row) * ldb + (k0 + c * 8), sB + idx * 8);
    }
    __syncthreads();

    u16x8 av[FM], bv[FN];
#pragma unroll
    for (int mi = 0; mi < FM; ++mi) {
      int row = wr * WM + mi * 16 + l15;
      int ch = row * 4 + (lhi ^ ((row >> 1) & 3));
      av[mi] = *(const u16x8*)(sA + ch * 8);
    }
#pragma unroll
    for (int ni = 0; ni < FN; ++ni) {
      int row = wc * WN + ni * 16 + l15;
      int ch = row * 4 + (lhi ^ ((row >> 1) & 3));
      bv[ni] = *(const u16x8*)(sB + ch * 8);
    }
#pragma unroll
    for (int mi = 0; mi < FM; ++mi)
#pragma unroll
      for (int ni = 0; ni < FN; ++ni) acc[mi][ni] = mfma_bf16(av[mi], bv[ni], acc[mi][ni]);
  }

  asm volatile("s_nop 7\ns_nop 7\ns_nop 7");  // MFMA->VALU hazard guard

#pragma unroll
  for (int mi = 0; mi < FM; ++mi) {
#pragma unroll
    for (int ni = 0; ni < FN; ++ni) {
      int col = n0 + wc * WN + ni * 16 + l15;
      if (col < Nreal) {
        float bvv = (OUT_MODE == 1) ? bias[col] : 0.f;
#pragma unroll
        for (int r = 0; r < 4; ++r) {
          int row = m0 + wr * WM + mi * 16 + lhi * 4 + r;
          float v = acc[mi][ni][r] + bvv;
          if (OUT_MODE == 2)
            Cb[(size_t)row * ldc + col] = f2bf(v);
          else
            Cf[(size_t)row * ldc + col] = v;
        }
      }
    }
  }
}

// ---------------- kA: hp + gh GEMM, BM=32 BN=128 BK=128 ----------------
// [hp|gh][256, 2560] = h[256,512] @ [W_h2h;W_hh]^T ; hp gets +b_h2h.
// grid 160: b0 = (bid/20)*32, n0 = (bid%20)*128. 4 K-iters.
__global__ __launch_bounds__(256) void kA_hpgh(const u16* __restrict__ hb,
                                               const u16* __restrict__ Whcatb,
                                               const float* __restrict__ b_h2h,
                                               float* __restrict__ hpbuf,
                                               float* __restrict__ ghbuf) {
  __shared__ __align__(16) u16 sA[32 * 128];   // 8 KB
  __shared__ __align__(16) u16 sB[128 * 128];  // 32 KB
  const int tid = threadIdx.x;
  const int lane = tid & 63, wave = tid >> 6;
  const int wr = wave >> 1, wc = wave & 1;  // WM=16, WN=64
  const int l15 = lane & 15, lhi = lane >> 4;
  const int b0 = ((int)blockIdx.x / 20) * 32, n0 = ((int)blockIdx.x % 20) * 128;

  f32x4 acc[4];
#pragma unroll
  for (int j = 0; j < 4; ++j) acc[j] = 0.f;

  for (int k0 = 0; k0 < 512; k0 += 128) {
    __syncthreads();
#pragma unroll
    for (int j = 0; j < 2; ++j) {  // A: 32 rows x 16 chunks
      int idx = j * 256 + tid, row = idx >> 4, cc = idx & 15, c = cc ^ (row & 15);
      gload_lds16(hb + (size_t)(b0 + row) * 512 + k0 + c * 8, sA + idx * 8);
    }
#pragma unroll
    for (int j = 0; j < 8; ++j) {  // B: 128 rows x 16 chunks
      int idx = j * 256 + tid, row = idx >> 4, cc = idx & 15, c = cc ^ (row & 15);
      gload_lds16(Whcatb + (size_t)(n0 + row) * 512 + k0 + c * 8, sB + idx * 8);
    }
    __syncthreads();
#pragma unroll
    for (int ks = 0; ks < 4; ++ks) {
      u16x8 av, bv[4];
      {
        int row = wr * 16 + l15;
        int ch = row * 16 + ((ks * 4 + lhi) ^ (row & 15));
        av = *(const u16x8*)(sA + ch * 8);
      }
#pragma unroll
      for (int ni = 0; ni < 4; ++ni) {
        int row = wc * 64 + ni * 16 + l15;
        int ch = row * 16 + ((ks * 4 + lhi) ^ (row & 15));
        bv[ni] = *(const u16x8*)(sB + ch * 8);
      }
#pragma unroll
      for (int ni = 0; ni < 4; ++ni) acc[ni] = mfma_bf16(av, bv[ni], acc[ni]);
    }
  }
  asm volatile("s_nop 7\ns_nop 7\ns_nop 7");
#pragma unroll
  for (int ni = 0; ni < 4; ++ni) {
    int col = n0 + wc * 64 + ni * 16 + l15;
    int rowg = b0 + wr * 16 + lhi * 4;
    if (col < 512) {
      float bvv = b_h2h[col];
#pragma unroll
      for (int r = 0; r < 4; ++r)
        hpbuf[(size_t)(rowg + r) * 512 + col] = acc[ni][r] + bvv;
    } else {
#pragma unroll
      for (int r = 0; r < 4; ++r)
        ghbuf[(size_t)(rowg + r) * 2048 + col - 512] = acc[ni][r];
    }
  }
}

// ---------------- kB: attention ----------------
// block b: e[t] = sum_h tanh(Hproj[b,t,h] + hp[b,h]) * w_score[h]; alpha = softmax;
// ctx = sum_t alpha[t]*bH[b,t,:] -> ctxb (bf16).
__global__ __launch_bounds__(256) void kB_attn(const u16* __restrict__ Hproj,
                                               const float* __restrict__ hpbuf,
                                               const float* __restrict__ wsc,
                                               const u16* __restrict__ bh,
                                               u16* __restrict__ ctxb) {
  const int b = blockIdx.x, tid = threadIdx.x;
  __shared__ float hpsp[528];  // padded: j -> j + (j>>5)
  __shared__ float wssp[528];
  __shared__ float es[64];

  {
    int j0 = tid * 2;
    hpsp[j0 + (j0 >> 5)] = hpbuf[(size_t)b * 512 + j0];
    hpsp[j0 + 1 + ((j0 + 1) >> 5)] = hpbuf[(size_t)b * 512 + j0 + 1];
    int pi = j0 + (j0 >> 5);
    wssp[pi] = wsc[j0];
    wssp[pi + 1] = wsc[j0 + 1];
  }
  __syncthreads();

  const int ch16 = tid & 15;
  const int hbase = ch16 * 33;
  const int hc = ch16 * 32;
  float hpr[32], wsr[32];
#pragma unroll
  for (int j = 0; j < 32; ++j) {
    hpr[j] = hpsp[hbase + j];
    wsr[j] = wssp[hbase + j];
  }
#pragma unroll
  for (int tg = 0; tg < 4; ++tg) {
    int t = tg * 16 + (tid >> 4);
    const u16* hr = Hproj + (size_t)(b * 64 + t) * 512 + hc;
    float s = 0.f;
#pragma unroll
    for (int jo = 0; jo < 32; jo += 8) {
      u16x8 hv = *(const u16x8*)(hr + jo);
#pragma unroll
      for (int j = 0; j < 8; ++j) {
        float x = bf2f(hv[j]) + hpr[jo + j];
        s += fast_tanh(x) * wsr[jo + j];
      }
    }
#pragma unroll
    for (int off = 8; off; off >>= 1) s += __shfl_xor(s, off, 16);
    if (ch16 == 0) es[t] = s;
  }
  __syncthreads();
  if (tid < 64) {  // softmax over t
    float v = es[tid];
    float m = v;
#pragma unroll
    for (int o = 32; o; o >>= 1) m = fmaxf(m, __shfl_xor(m, o, 64));
    float p = __expf(v - m);
    float su = p;
#pragma unroll
    for (int o = 32; o; o >>= 1) su += __shfl_xor(su, o, 64);
    es[tid] = p / su;
  }
  __syncthreads();
  const u16* base = bh + (size_t)b * 32768 + tid * 2;
  float c0 = 0.f, c1 = 0.f;
#pragma unroll 8
  for (int t = 0; t < 64; ++t) {
    u32 w = *(const u32*)(base + t * 512);
    float a = es[t];
    c0 = fmaf(a, bf2f((u16)(w & 0xffffu)), c0);
    c1 = fmaf(a, bf2f((u16)(w >> 16)), c1);
  }
  u32 pk = (u32)f2bf(c0) | ((u32)f2bf(c1) << 16);
  *(u32*)(ctxb + (size_t)b * 512 + tid * 2) = pk;
}

// ---------------- kC: gates_ctx GEMM (K=512, BK=128) + gh + E2G gather + LSTM ----------------
// grid (16, 8): jt = 32-wide j-tile (x4 gate segs -> BN=128), b0 = 32-wide batch tile.
__global__ __launch_bounds__(256) void kC_gates_lstm(const u16* __restrict__ ctxb,
                                                     const u16* __restrict__ Wctxb,
                                                     const float* __restrict__ E2G,
                                                     const float* __restrict__ ghbuf,
                                                     const int* __restrict__ text,
                                                     float* __restrict__ cst,
                                                     u16* __restrict__ hb,
                                                     u16* __restrict__ hsb, int step) {
  __shared__ __align__(16) char smem[40960];  // sA 8KB + sB 32KB; reused: gsm 32x132 f32
  u16* sA = (u16*)smem;           // 32 x 128
  u16* sB = (u16*)(smem + 8192);  // 128 x 128
  const int tid = threadIdx.x;
  const int lane = tid & 63, wave = tid >> 6;
  const int wr = wave >> 1, wc = wave & 1;  // WM=16, WN=64
  const int l15 = lane & 15, lhi = lane >> 4;
  const int jt = blockIdx.x;
  const int b0 = blockIdx.y * 32;

  f32x4 acc[4];
#pragma unroll
  for (int j = 0; j < 4; ++j) acc[j] = 0.f;

  for (int k0 = 0; k0 < 512; k0 += 128) {
    __syncthreads();
#pragma unroll
    for (int j = 0; j < 2; ++j) {  // A: 32 rows x 16 chunks
      int idx = j * 256 + tid, row = idx >> 4, cc = idx & 15, c = cc ^ (row & 15);
      gload_lds16(ctxb + (size_t)(b0 + row) * 512 + k0 + c * 8, sA + idx * 8);
    }
#pragma unroll
    for (int j = 0; j < 8; ++j) {  // B: 128 rows (4 segs x 32 j) x 16 chunks
      int idx = j * 256 + tid, row = idx >> 4, cc = idx & 15, c = cc ^ (row & 15);
      int grow = (row >> 5) * 512 + jt * 32 + (row & 31);
      gload_lds16(Wctxb + (size_t)grow * 512 + k0 + c * 8, sB + idx * 8);
    }
    __syncthreads();

#pragma unroll
    for (int ks = 0; ks < 4; ++ks) {
      u16x8 av, bv[4];
      {
        int row = wr * 16 + l15;
        int ch = row * 16 + ((ks * 4 + lhi) ^ (row & 15));
        av = *(const u16x8*)(sA + ch * 8);
      }
#pragma unroll
      for (int ni = 0; ni < 4; ++ni) {
        int row = wc * 64 + ni * 16 + l15;
        int ch = row * 16 + ((ks * 4 + lhi) ^ (row & 15));
        bv[ni] = *(const u16x8*)(sB + ch * 8);
      }
#pragma unroll
      for (int ni = 0; ni < 4; ++ni) acc[ni] = mfma_bf16(av, bv[ni], acc[ni]);
    }
  }

  asm volatile("s_nop 7\ns_nop 7\ns_nop 7");  // MFMA->VALU hazard guard
  __syncthreads();                            // staging reads done -> reuse LDS
  float (*gsm)[132] = (float(*)[132])smem;    // 32 x 132 f32 = 16.9 KB
#pragma unroll
  for (int ni = 0; ni < 4; ++ni) {
    int col = wc * 64 + ni * 16 + l15;
    int row = wr * 16 + lhi * 4;
#pragma unroll
    for (int r = 0; r < 4; ++r) gsm[row + r][col] = acc[ni][r];
  }
  __syncthreads();

  {  // LSTM: thread owns bl = tid>>3, 4 j's at jl0 = (tid&7)*4
    const int bl = tid >> 3, jl0 = (tid & 7) * 4;
    const int b = b0 + bl;
    const int jg0 = jt * 32 + jl0;
    const int ci = text[b * 26 + step];
    const float* gh = ghbuf + (size_t)b * 2048;
    const float* ge = E2G + (size_t)ci * 2048;  // includes biascat
    float cn[4];
    u16 hbv[4];
#pragma unroll
    for (int q = 0; q < 4; ++q) {
      int jl = jl0 + q, j = jg0 + q;
      float gi = gsm[bl][jl]      + gh[j]        + ge[j];
      float gf = gsm[bl][32 + jl] + gh[512 + j]  + ge[512 + j];
      float gg = gsm[bl][64 + jl] + gh[1024 + j] + ge[1024 + j];
      float go = gsm[bl][96 + jl] + gh[1536 + j] + ge[1536 + j];
      float c = fast_sig(gf) * cst[(size_t)b * 512 + j] + fast_sig(gi) * fast_tanh(gg);
      cn[q] = c;
      hbv[q] = f2bf(fast_sig(go) * fast_tanh(c));
    }
    *(f32x4*)(cst + (size_t)b * 512 + jg0) = *(f32x4*)cn;
    *(u16x4*)(hb + (size_t)b * 512 + jg0) = *(u16x4*)hbv;
    *(u16x4*)(hsb + (size_t)(b * 26 + step) * 512 + jg0) = *(u16x4*)hbv;
  }
}

// ---------------- launch ----------------
extern "C" void kernel_launch(void* const* d_in, const int* in_sizes, int n_in,
                              void* d_out, int out_size, void* d_ws, size_t ws_size,
                              hipStream_t stream) {
  const float* batch_H = (const float*)d_in[0];
  const int*   text    = (const int*)d_in[1];
  const float* W_i2h   = (const float*)d_in[2];
  const float* W_h2h   = (const float*)d_in[3];
  const float* b_h2h   = (const float*)d_in[4];
  const float* w_score = (const float*)d_in[5];
  const float* W_ih    = (const float*)d_in[6];
  const float* W_hh    = (const float*)d_in[7];
  const float* b_ih    = (const float*)d_in[8];
  const float* b_hh    = (const float*)d_in[9];
  const float* emb     = (const float*)d_in[10];
  const float* W_gen   = (const float*)d_in[11];
  const float* b_gen   = (const float*)d_in[12];
  float* out = (float*)d_out;

  // Big bf16 scratch at the front of d_out (fully overwritten by the final GEMM,
  // which reads only hsb/Wgenb).
  u16* bHb   = (u16*)d_out;          // 16 MB
  u16* Hproj = bHb + 8388608;        // 16 MB

  char* w = (char*)d_ws;
  auto alloc = [&](size_t bytes) {
    char* p = w;
    w += (bytes + 255) & ~(size_t)255;
    return p;
  };
  u16*   Wi2hb   = (u16*)alloc(512ull * 512 * 2);
  u16*   Whcatb  = (u16*)alloc(2560ull * 512 * 2);   // [W_h2h ; W_hh]
  u16*   Wctxb   = (u16*)alloc(2048ull * 512 * 2);   // W_ih[:, 0:512]
  u16*   Wceb    = (u16*)alloc(2048ull * 256 * 2);   // W_ih[:, 512:768]
  u16*   Wgenb   = (u16*)alloc(6656ull * 512 * 2);
  u16*   embb    = (u16*)alloc(6656ull * 256 * 2);   // padded rows >= 6624
  float* biascat = (float*)alloc(2048ull * 4);
  u16*   ctxb    = (u16*)alloc(256ull * 512 * 2);
  u16*   hb      = (u16*)alloc(256ull * 512 * 2);
  float* cst     = (float*)alloc(256ull * 512 * 4);
  float* hpbuf   = (float*)alloc(256ull * 512 * 4);
  float* ghbuf   = (float*)alloc(256ull * 2048 * 4);
  u16*   hsb     = (u16*)alloc(6656ull * 512 * 2);
  float* E2G     = (float*)alloc(6656ull * 2048 * 4);  // emb@W_ce^T + biascat

  // 1) fused prep
  k_prep<<<16450, 256, 0, stream>>>(batch_H, W_i2h, emb, W_ih, W_h2h, W_hh, W_gen,
                                    b_ih, b_hh, bHb, Wi2hb, embb, Wctxb, Wceb,
                                    Whcatb, Wgenb, biascat, hb, cst);

  // 2) Hproj = batch_H @ W_i2h^T -> bf16
  gemm_bt<128, 128, 64, 64, 2><<<dim3(4, 128), 256, 0, stream>>>(
      bHb, 512, Wi2hb, 512, nullptr, nullptr, Hproj, 512, 512, 512);

  // 2b) E2G = emb @ W_ce^T + biascat (per-class ce gate contribution, hoisted)
  gemm_bt<128, 128, 64, 64, 1><<<dim3(16, 52), 256, 0, stream>>>(
      embb, 256, Wceb, 256, biascat, E2G, nullptr, 2048, 2048, 256);

  // 3) recurrence: 3 small kernels per step
  for (int s = 0; s < 26; ++s) {
    kA_hpgh<<<160, 256, 0, stream>>>(hb, Whcatb, b_h2h, hpbuf, ghbuf);
    kB_attn<<<256, 256, 0, stream>>>(Hproj, hpbuf, w_score, bHb, ctxb);
    kC_gates_lstm<<<dim3(16, 8), 256, 0, stream>>>(ctxb, Wctxb, E2G, ghbuf, text,
                                                   cst, hb, hsb, s);
  }

  // 4) probs = hs @ W_gen^T + b_gen -> f32 out (M=6656, N=6624, K=512)
  gemm_bt<128, 128, 64, 64, 1><<<dim3(52, 52), 256, 0, stream>>>(
      hsb, 512, Wgenb, 512, b_gen, out, nullptr, 6624, 6624, 512);

  (void)in_sizes; (void)n_in; (void)out_size; (void)ws_size;
}